// Round 1
// baseline (11336.927 us; speedup 1.0000x reference)
//
#include <hip/hip_runtime.h>
#include <cstdint>
#include <cstddef>

#define B_ 64
#define S_ 512
#define I_ 256
#define H_ 512
#define E_ 512

// ---------------- transpose 512x512 (fp32): out[k*512+j] = in[j*512+k] ----------------
__global__ __launch_bounds__(256) void transpose512(const float* __restrict__ in,
                                                    float* __restrict__ out) {
    __shared__ float tile[32][33];
    int tx = threadIdx.x, ty = threadIdx.y;
    int x = blockIdx.x * 32 + tx;
    int y0 = blockIdx.y * 32 + ty;
#pragma unroll
    for (int j = 0; j < 32; j += 8)
        tile[ty + j][tx] = in[(size_t)(y0 + j) * 512 + x];
    __syncthreads();
    int x2 = blockIdx.y * 32 + tx;
    int y2 = blockIdx.x * 32 + ty;
#pragma unroll
    for (int j = 0; j < 32; j += 8)
        out[(size_t)(y2 + j) * 512 + x2] = tile[tx][ty + j];
}

// ---------------- xw GEMM: xw[(s*B+b)*H + h] = sum_i x[b][s][i]*W_ih[h][i] + b_ih[h] + b_hh[h]
// M = S*B = 32768 (m = s*64 + b), N = H = 512, K = I = 256.
// BM=BN=64, BK=16, 256 threads, 4x4 microtile.
__global__ __launch_bounds__(256) void xw_gemm(const float* __restrict__ x,
                                               const float* __restrict__ W_ih,
                                               const float* __restrict__ b_ih,
                                               const float* __restrict__ b_hh,
                                               float* __restrict__ xw) {
    __shared__ float As[16][65];
    __shared__ float Bs[16][65];
    const int tid = threadIdx.x;
    const int m0 = blockIdx.y * 64;
    const int n0 = blockIdx.x * 64;

    const int lr = tid >> 2;          // 0..63 (row within tile)
    const int lk = (tid & 3) * 4;     // 0,4,8,12

    const int m = m0 + lr;            // m = s*64 + b  ->  b = m & 63, s = m >> 6
    const float* xrow = x + ((size_t)(m & 63) * S_ + (m >> 6)) * I_;
    const float* brow = W_ih + (size_t)(n0 + lr) * I_;

    const int tm = (tid >> 4) * 4;    // 0..60
    const int tn = (tid & 15) * 4;    // 0..60

    float acc[4][4] = {{0.f}};

    for (int kt = 0; kt < I_; kt += 16) {
        float4 av = *(const float4*)(xrow + kt + lk);
        float4 bv = *(const float4*)(brow + kt + lk);
        As[lk + 0][lr] = av.x; As[lk + 1][lr] = av.y;
        As[lk + 2][lr] = av.z; As[lk + 3][lr] = av.w;
        Bs[lk + 0][lr] = bv.x; Bs[lk + 1][lr] = bv.y;
        Bs[lk + 2][lr] = bv.z; Bs[lk + 3][lr] = bv.w;
        __syncthreads();
#pragma unroll
        for (int k = 0; k < 16; ++k) {
            float a0 = As[k][tm + 0], a1 = As[k][tm + 1], a2 = As[k][tm + 2], a3 = As[k][tm + 3];
            float c0 = Bs[k][tn + 0], c1 = Bs[k][tn + 1], c2 = Bs[k][tn + 2], c3 = Bs[k][tn + 3];
            acc[0][0] += a0 * c0; acc[0][1] += a0 * c1; acc[0][2] += a0 * c2; acc[0][3] += a0 * c3;
            acc[1][0] += a1 * c0; acc[1][1] += a1 * c1; acc[1][2] += a1 * c2; acc[1][3] += a1 * c3;
            acc[2][0] += a2 * c0; acc[2][1] += a2 * c1; acc[2][2] += a2 * c2; acc[2][3] += a2 * c3;
            acc[3][0] += a3 * c0; acc[3][1] += a3 * c1; acc[3][2] += a3 * c2; acc[3][3] += a3 * c3;
        }
        __syncthreads();
    }

#pragma unroll
    for (int i = 0; i < 4; ++i) {
        int row = m0 + tm + i;
#pragma unroll
        for (int j = 0; j < 4; ++j) {
            int n = n0 + tn + j;
            xw[(size_t)row * H_ + n] = acc[i][j] + b_ih[n] + b_hh[n];
        }
    }
}

// ---------------- sequential scan: one workgroup per batch element ----------------
// 512 threads: jg = tid & 127 owns outputs j = 4*jg..4*jg+3 ; ks = tid >> 7 owns k-slice
// [128*ks, 128*ks+128). Weights pre-transposed: WT[k*512 + j].
__global__ __launch_bounds__(512) void scan_kernel(const float* __restrict__ xw,
                                                   const float* __restrict__ WhhT,
                                                   const float* __restrict__ WyaT,
                                                   const float* __restrict__ WaaT,
                                                   const float* __restrict__ b_ya,
                                                   const float* __restrict__ b_aa,
                                                   float* __restrict__ out) {
    const int b = blockIdx.x;
    const int tid = threadIdx.x;
    const int jg = tid & 127;
    const int ks = tid >> 7;
    const int kbase = ks * 128;

    __shared__ float h[512];
    __shared__ float a[512];
    __shared__ float4 part[512];   // [ks][128] float4 partials
    float* partf = (float*)part;

    h[tid] = 0.f;
    a[tid] = 0.f;
    const float bias_a = b_ya[tid] + b_aa[tid];   // used with j = tid in reduce phase
    __syncthreads();

    const float4* Wh4 = (const float4*)WhhT;
    const float4* Wy4 = (const float4*)WyaT;
    const float4* Wa4 = (const float4*)WaaT;

    for (int t = 0; t < S_; ++t) {
        // ---- h_t = tanh(xw_t + W_hh h_{t-1}) ----
        float4 acc = {0.f, 0.f, 0.f, 0.f};
#pragma unroll 4
        for (int k = 0; k < 128; ++k) {
            float hv = h[kbase + k];
            float4 w = Wh4[(size_t)(kbase + k) * 128 + jg];
            acc.x += hv * w.x; acc.y += hv * w.y; acc.z += hv * w.z; acc.w += hv * w.w;
        }
        part[ks * 128 + jg] = acc;
        __syncthreads();
        {
            int j = tid;
            float s = partf[j] + partf[512 + j] + partf[1024 + j] + partf[1536 + j];
            float xwv = xw[((size_t)t * B_ + b) * H_ + j];
            h[j] = tanhf(xwv + s);
        }
        __syncthreads();

        // ---- a_t = tanh(W_ya h_t + b_ya + W_aa a_{t-1} + b_aa) ----
        float4 acc2 = {0.f, 0.f, 0.f, 0.f};
#pragma unroll 4
        for (int k = 0; k < 128; ++k) {
            float hv = h[kbase + k];
            float4 w = Wy4[(size_t)(kbase + k) * 128 + jg];
            acc2.x += hv * w.x; acc2.y += hv * w.y; acc2.z += hv * w.z; acc2.w += hv * w.w;
        }
#pragma unroll 4
        for (int k = 0; k < 128; ++k) {
            float av = a[kbase + k];
            float4 w = Wa4[(size_t)(kbase + k) * 128 + jg];
            acc2.x += av * w.x; acc2.y += av * w.y; acc2.z += av * w.z; acc2.w += av * w.w;
        }
        part[ks * 128 + jg] = acc2;
        __syncthreads();
        {
            int j = tid;
            float s = partf[j] + partf[512 + j] + partf[1024 + j] + partf[1536 + j];
            a[j] = tanhf(bias_a + s);
        }
        __syncthreads();
    }

    out[(size_t)b * E_ + tid] = a[tid];
}

extern "C" void kernel_launch(void* const* d_in, const int* in_sizes, int n_in,
                              void* d_out, int out_size, void* d_ws, size_t ws_size,
                              hipStream_t stream) {
    const float* x    = (const float*)d_in[0];
    const float* W_ih = (const float*)d_in[1];
    const float* W_hh = (const float*)d_in[2];
    const float* b_ih = (const float*)d_in[3];
    const float* b_hh = (const float*)d_in[4];
    const float* W_ya = (const float*)d_in[5];
    const float* b_ya = (const float*)d_in[6];
    const float* W_aa = (const float*)d_in[7];
    const float* b_aa = (const float*)d_in[8];
    float* out = (float*)d_out;

    char* ws = (char*)d_ws;
    float* xw   = (float*)(ws);                                 // 64 MB (S*B*H fp32)
    float* WhhT = (float*)(ws + (size_t)64 * 1024 * 1024);      // 1 MB
    float* WyaT = (float*)(ws + (size_t)65 * 1024 * 1024);      // 1 MB
    float* WaaT = (float*)(ws + (size_t)66 * 1024 * 1024);      // 1 MB

    dim3 tb(32, 8);
    dim3 tg(16, 16);
    transpose512<<<tg, tb, 0, stream>>>(W_hh, WhhT);
    transpose512<<<tg, tb, 0, stream>>>(W_ya, WyaT);
    transpose512<<<tg, tb, 0, stream>>>(W_aa, WaaT);

    dim3 gg(H_ / 64, (S_ * B_) / 64);   // (8, 512)
    xw_gemm<<<gg, 256, 0, stream>>>(x, W_ih, b_ih, b_hh, xw);

    scan_kernel<<<64, 512, 0, stream>>>(xw, WhhT, WyaT, WaaT, b_ya, b_aa, out);
}

// Round 2
// 7584.118 us; speedup vs baseline: 1.4948x; 1.4948x over previous
//
#include <hip/hip_runtime.h>
#include <cstdint>
#include <cstddef>

#define B_ 64
#define S_ 512
#define I_ 256
#define H_ 512
#define E_ 512

typedef __attribute__((ext_vector_type(8))) short bf16x8;
typedef __attribute__((ext_vector_type(4))) float f32x4;

__device__ __forceinline__ unsigned short f2b(float x) {
    uint32_t u = __builtin_bit_cast(uint32_t, x);
    uint32_t r = u + 0x7fffu + ((u >> 16) & 1u);
    return (unsigned short)(r >> 16);
}

// ---- convert the three 512x512 recurrent matrices to bf16 (row-major, unchanged layout) ----
__global__ __launch_bounds__(256) void conv_bf16(const float* __restrict__ whh,
                                                 const float* __restrict__ wya,
                                                 const float* __restrict__ waa,
                                                 unsigned short* __restrict__ owhh,
                                                 unsigned short* __restrict__ owya,
                                                 unsigned short* __restrict__ owaa) {
    int i = blockIdx.x * 256 + threadIdx.x;   // 0 .. 262143
    owhh[i] = f2b(whh[i]);
    owya[i] = f2b(wya[i]);
    owaa[i] = f2b(waa[i]);
}

// ---- zero h/a state buffers + barrier counters (ws is poisoned 0xAA each launch) ----
__global__ __launch_bounds__(256) void init_state(uint32_t* __restrict__ p, int n) {
    int i = blockIdx.x * 256 + threadIdx.x;
    if (i < n) p[i] = 0u;
}

// ---------------- xw GEMM (fp32, unchanged from round 1 — verified correct) ----------------
__global__ __launch_bounds__(256) void xw_gemm(const float* __restrict__ x,
                                               const float* __restrict__ W_ih,
                                               const float* __restrict__ b_ih,
                                               const float* __restrict__ b_hh,
                                               float* __restrict__ xw) {
    __shared__ float As[16][65];
    __shared__ float Bs[16][65];
    const int tid = threadIdx.x;
    const int m0 = blockIdx.y * 64;
    const int n0 = blockIdx.x * 64;

    const int lr = tid >> 2;
    const int lk = (tid & 3) * 4;

    const int m = m0 + lr;
    const float* xrow = x + ((size_t)(m & 63) * S_ + (m >> 6)) * I_;
    const float* brow = W_ih + (size_t)(n0 + lr) * I_;

    const int tm = (tid >> 4) * 4;
    const int tn = (tid & 15) * 4;

    float acc[4][4] = {{0.f}};

    for (int kt = 0; kt < I_; kt += 16) {
        float4 av = *(const float4*)(xrow + kt + lk);
        float4 bv = *(const float4*)(brow + kt + lk);
        As[lk + 0][lr] = av.x; As[lk + 1][lr] = av.y;
        As[lk + 2][lr] = av.z; As[lk + 3][lr] = av.w;
        Bs[lk + 0][lr] = bv.x; Bs[lk + 1][lr] = bv.y;
        Bs[lk + 2][lr] = bv.z; Bs[lk + 3][lr] = bv.w;
        __syncthreads();
#pragma unroll
        for (int k = 0; k < 16; ++k) {
            float a0 = As[k][tm + 0], a1 = As[k][tm + 1], a2 = As[k][tm + 2], a3 = As[k][tm + 3];
            float c0 = Bs[k][tn + 0], c1 = Bs[k][tn + 1], c2 = Bs[k][tn + 2], c3 = Bs[k][tn + 3];
            acc[0][0] += a0 * c0; acc[0][1] += a0 * c1; acc[0][2] += a0 * c2; acc[0][3] += a0 * c3;
            acc[1][0] += a1 * c0; acc[1][1] += a1 * c1; acc[1][2] += a1 * c2; acc[1][3] += a1 * c3;
            acc[2][0] += a2 * c0; acc[2][1] += a2 * c1; acc[2][2] += a2 * c2; acc[2][3] += a2 * c3;
            acc[3][0] += a3 * c0; acc[3][1] += a3 * c1; acc[3][2] += a3 * c2; acc[3][3] += a3 * c3;
        }
        __syncthreads();
    }

#pragma unroll
    for (int i = 0; i < 4; ++i) {
        int row = m0 + tm + i;
#pragma unroll
        for (int j = 0; j < 4; ++j) {
            int n = n0 + tn + j;
            xw[(size_t)row * H_ + n] = acc[i][j] + b_ih[n] + b_hh[n];
        }
    }
}

// ---------------- MFMA scan ----------------
// Grid = 128 WGs: wg = bg*32 + jg ; bg in [0,4) owns b rows [16bg,16bg+16),
// jg in [0,32) owns j cols [16jg,16jg+16). Block = 128 threads (2 waves).
// Lagged recurrence: step t computes h_t (wave 0) and a_{t-1} (wave 1), both
// functions of step-(t-1) state only -> one 32-WG barrier per step (4 groups).
// Weights live in LDS as pre-formatted MFMA B-fragments (bf16), loaded once.
// State h/a is double-buffered bf16 [64][512] row-major in global ws.
__global__ __launch_bounds__(128) void scan_mfma(const float* __restrict__ xw,
                                                 const unsigned short* __restrict__ Whh_b,
                                                 const unsigned short* __restrict__ Wya_b,
                                                 const unsigned short* __restrict__ Waa_b,
                                                 const float* __restrict__ b_ya,
                                                 const float* __restrict__ b_aa,
                                                 unsigned short* __restrict__ hb,   // 2*64*512 bf16
                                                 unsigned short* __restrict__ ab,   // 2*64*512 bf16
                                                 int* __restrict__ ctr,             // 4 counters, 256B apart
                                                 float* __restrict__ out) {
    const int wg   = blockIdx.x;
    const int bg   = wg >> 5;
    const int jg   = wg & 31;
    const int b0   = bg * 16;
    const int j0   = jg * 16;
    const int tid  = threadIdx.x;
    const int wave = tid >> 6;
    const int lane = tid & 63;
    const int l15  = lane & 15;
    const int quad = lane >> 4;

    // B-fragment LDS: [mat][kblock][lane] 8 bf16 each. mat: 0=Whh 1=Wya 2=Waa.
    __shared__ unsigned short wlds[3 * 16 * 64 * 8];   // 48 KB
    __shared__ float pya[256];                          // wave0's Wya·h partial tile

    // Stage weight B-frags once. B[k][n=j] = W[j][k]; lane holds
    // W[j0 + (lane&15)][kb*32 + quad*8 .. +7] = 16 contiguous bytes of row-major bf16 W.
    {
        const unsigned short* wsrc[3] = {Whh_b, Wya_b, Waa_b};
        for (int idx = wave; idx < 48; idx += 2) {
            int mat = idx >> 4, kb = idx & 15;
            const unsigned short* src = wsrc[mat] + (size_t)(j0 + l15) * H_ + kb * 32 + quad * 8;
            *(uint4*)&wlds[((mat * 16 + kb) * 64 + lane) * 8] = *(const uint4*)src;
        }
    }
    const float bias_a = b_ya[j0 + l15] + b_aa[j0 + l15];
    volatile int* myctr = ctr + bg * 64;   // 256-byte spread
    __syncthreads();

    for (int t = 1; t <= S_ + 1; ++t) {
        f32x4 acca = {0.f, 0.f, 0.f, 0.f};
        const bool have_a = (wave == 1) && (t >= 2);

        if (wave == 0) {
            // h_{t-1} A-frags: lane holds h[b0+(lane&15)][kb*32 + quad*8 ..+7]
            const unsigned short* hsrc = hb + (size_t)((t - 1) & 1) * (B_ * H_)
                                            + (size_t)(b0 + l15) * H_ + quad * 8;
            f32x4 acch = {0.f, 0.f, 0.f, 0.f};
            f32x4 accy = {0.f, 0.f, 0.f, 0.f};
#pragma unroll
            for (int kb = 0; kb < 16; ++kb) {
                bf16x8 af = *(const bf16x8*)(hsrc + kb * 32);
                bf16x8 bh = *(const bf16x8*)&wlds[((0 * 16 + kb) * 64 + lane) * 8];
                bf16x8 by = *(const bf16x8*)&wlds[((1 * 16 + kb) * 64 + lane) * 8];
                acch = __builtin_amdgcn_mfma_f32_16x16x32_bf16(af, bh, acch, 0, 0, 0);
                accy = __builtin_amdgcn_mfma_f32_16x16x32_bf16(af, by, accy, 0, 0, 0);
            }
#pragma unroll
            for (int r = 0; r < 4; ++r)
                pya[(quad * 4 + r) * 16 + l15] = accy[r];
            if (t <= S_) {
                unsigned short* hdst = hb + (size_t)(t & 1) * (B_ * H_);
#pragma unroll
                for (int r = 0; r < 4; ++r) {
                    int brow = b0 + quad * 4 + r;
                    float pre = xw[((size_t)(t - 1) * B_ + brow) * H_ + (j0 + l15)] + acch[r];
                    hdst[(size_t)brow * H_ + (j0 + l15)] = f2b(tanhf(pre));
                }
            }
        } else if (have_a) {
            // a_{t-2} A-frags
            const unsigned short* asrc = ab + (size_t)(t & 1) * (B_ * E_)
                                            + (size_t)(b0 + l15) * E_ + quad * 8;
#pragma unroll
            for (int kb = 0; kb < 16; ++kb) {
                bf16x8 af = *(const bf16x8*)(asrc + kb * 32);
                bf16x8 ba = *(const bf16x8*)&wlds[((2 * 16 + kb) * 64 + lane) * 8];
                acca = __builtin_amdgcn_mfma_f32_16x16x32_bf16(af, ba, acca, 0, 0, 0);
            }
        }
        __syncthreads();   // pya visible to wave 1

        if (have_a) {
            unsigned short* adst = ab + (size_t)((t - 1) & 1) * (B_ * E_);
#pragma unroll
            for (int r = 0; r < 4; ++r) {
                int row = quad * 4 + r;
                float v = acca[r] + pya[row * 16 + l15] + bias_a;
                float av = tanhf(v);
                if (t <= S_)
                    adst[(size_t)(b0 + row) * E_ + (j0 + l15)] = f2b(av);
                else
                    out[(size_t)(b0 + row) * E_ + (j0 + l15)] = av;
            }
        }

        if (t <= S_) {
            __syncthreads();   // all this step's stores issued & drained (vmcnt(0) before barrier)
            if (tid == 0) {
                __threadfence();
                __hip_atomic_fetch_add((int*)myctr, 1, __ATOMIC_RELEASE, __HIP_MEMORY_SCOPE_AGENT);
                while (__hip_atomic_load((int*)myctr, __ATOMIC_ACQUIRE, __HIP_MEMORY_SCOPE_AGENT) < 32 * t) {}
            }
            __syncthreads();
            __threadfence();   // acquire: invalidate stale cached state before next step's reads
        }
    }
}

extern "C" void kernel_launch(void* const* d_in, const int* in_sizes, int n_in,
                              void* d_out, int out_size, void* d_ws, size_t ws_size,
                              hipStream_t stream) {
    const float* x    = (const float*)d_in[0];
    const float* W_ih = (const float*)d_in[1];
    const float* W_hh = (const float*)d_in[2];
    const float* b_ih = (const float*)d_in[3];
    const float* b_hh = (const float*)d_in[4];
    const float* W_ya = (const float*)d_in[5];
    const float* b_ya = (const float*)d_in[6];
    const float* W_aa = (const float*)d_in[7];
    const float* b_aa = (const float*)d_in[8];
    float* out = (float*)d_out;

    char* ws = (char*)d_ws;
    const size_t MB = 1024 * 1024;
    float*          xw    = (float*)(ws);                              // 64 MB
    unsigned short* Whh_b = (unsigned short*)(ws + 64 * MB);           // 512 KB
    unsigned short* Wya_b = (unsigned short*)(ws + 64 * MB + 512 * 1024);
    unsigned short* Waa_b = (unsigned short*)(ws + 65 * MB);
    unsigned short* hb    = (unsigned short*)(ws + 65 * MB + 512 * 1024);  // 128 KB
    unsigned short* ab    = (unsigned short*)(ws + 65 * MB + 640 * 1024);  // 128 KB
    int*            ctr   = (int*)(ws + 66 * MB);                          // 4 KB

    conv_bf16<<<(H_ * H_) / 256, 256, 0, stream>>>(W_hh, W_ya, W_aa, Whh_b, Wya_b, Waa_b);

    // zero: hb (128KB) + ab (128KB) + ctr (4KB) = 260 KB = 66560 u32
    init_state<<<261, 256, 0, stream>>>((uint32_t*)hb, 65536);   // hb+ab contiguous: 2*65536 ush = 65536 u32
    init_state<<<5,   256, 0, stream>>>((uint32_t*)ctr, 1024);

    dim3 gg(H_ / 64, (S_ * B_) / 64);
    xw_gemm<<<gg, 256, 0, stream>>>(x, W_ih, b_ih, b_hh, xw);

    scan_mfma<<<128, 128, 0, stream>>>(xw, Whh_b, Wya_b, Waa_b, b_ya, b_aa,
                                       hb, ab, ctr, out);
}

// Round 4
// 3599.365 us; speedup vs baseline: 3.1497x; 2.1071x over previous
//
#include <hip/hip_runtime.h>
#include <cstdint>
#include <cstddef>

#define B_ 64
#define S_ 512
#define I_ 256
#define H_ 512
#define E_ 512
#define GRP_WGS 16   // WGs per batch-group barrier

typedef __attribute__((ext_vector_type(8))) short bf16x8;
typedef __attribute__((ext_vector_type(4))) float f32x4;

__device__ __forceinline__ unsigned short f2b(float x) {
    uint32_t u = __builtin_bit_cast(uint32_t, x);
    uint32_t r = u + 0x7fffu + ((u >> 16) & 1u);
    return (unsigned short)(r >> 16);
}

// Compiler-only ordering: block IR + machine-level motion of LDS ops across
// this point. HW needs nothing (DS ops execute in order within a wave).
__device__ __forceinline__ void lds_repack_fence() {
    __atomic_signal_fence(__ATOMIC_SEQ_CST);
    __builtin_amdgcn_wave_barrier();
}

// ---- convert the three 512x512 recurrent matrices to bf16 (row-major) ----
__global__ __launch_bounds__(256) void conv_bf16(const float* __restrict__ whh,
                                                 const float* __restrict__ wya,
                                                 const float* __restrict__ waa,
                                                 unsigned short* __restrict__ owhh,
                                                 unsigned short* __restrict__ owya,
                                                 unsigned short* __restrict__ owaa) {
    int i = blockIdx.x * 256 + threadIdx.x;
    owhh[i] = f2b(whh[i]);
    owya[i] = f2b(wya[i]);
    owaa[i] = f2b(waa[i]);
}

__global__ __launch_bounds__(256) void init_state(uint32_t* __restrict__ p, int n) {
    int i = blockIdx.x * 256 + threadIdx.x;
    if (i < n) p[i] = 0u;
}

// ---------------- xw GEMM (fp32, unchanged — verified) ----------------
__global__ __launch_bounds__(256) void xw_gemm(const float* __restrict__ x,
                                               const float* __restrict__ W_ih,
                                               const float* __restrict__ b_ih,
                                               const float* __restrict__ b_hh,
                                               float* __restrict__ xw) {
    __shared__ float As[16][65];
    __shared__ float Bs[16][65];
    const int tid = threadIdx.x;
    const int m0 = blockIdx.y * 64;
    const int n0 = blockIdx.x * 64;

    const int lr = tid >> 2;
    const int lk = (tid & 3) * 4;

    const int m = m0 + lr;
    const float* xrow = x + ((size_t)(m & 63) * S_ + (m >> 6)) * I_;
    const float* brow = W_ih + (size_t)(n0 + lr) * I_;

    const int tm = (tid >> 4) * 4;
    const int tn = (tid & 15) * 4;

    float acc[4][4] = {{0.f}};

    for (int kt = 0; kt < I_; kt += 16) {
        float4 av = *(const float4*)(xrow + kt + lk);
        float4 bv = *(const float4*)(brow + kt + lk);
        As[lk + 0][lr] = av.x; As[lk + 1][lr] = av.y;
        As[lk + 2][lr] = av.z; As[lk + 3][lr] = av.w;
        Bs[lk + 0][lr] = bv.x; Bs[lk + 1][lr] = bv.y;
        Bs[lk + 2][lr] = bv.z; Bs[lk + 3][lr] = bv.w;
        __syncthreads();
#pragma unroll
        for (int k = 0; k < 16; ++k) {
            float a0 = As[k][tm + 0], a1 = As[k][tm + 1], a2 = As[k][tm + 2], a3 = As[k][tm + 3];
            float c0 = Bs[k][tn + 0], c1 = Bs[k][tn + 1], c2 = Bs[k][tn + 2], c3 = Bs[k][tn + 3];
            acc[0][0] += a0 * c0; acc[0][1] += a0 * c1; acc[0][2] += a0 * c2; acc[0][3] += a0 * c3;
            acc[1][0] += a1 * c0; acc[1][1] += a1 * c1; acc[1][2] += a1 * c2; acc[1][3] += a1 * c3;
            acc[2][0] += a2 * c0; acc[2][1] += a2 * c1; acc[2][2] += a2 * c2; acc[2][3] += a2 * c3;
            acc[3][0] += a3 * c0; acc[3][1] += a3 * c1; acc[3][2] += a3 * c2; acc[3][3] += a3 * c3;
        }
        __syncthreads();
    }

#pragma unroll
    for (int i = 0; i < 4; ++i) {
        int row = m0 + tm + i;
#pragma unroll
        for (int j = 0; j < 4; ++j) {
            int n = n0 + tn + j;
            xw[(size_t)row * H_ + n] = acc[i][j] + b_ih[n] + b_hh[n];
        }
    }
}

// ---------------- MFMA scan, relaxed-coherent state exchange ----------------
// 64 WGs x 256 threads. wg = bg*16 + jgrp. bg owns batch rows [16bg,16bg+16);
// jgrp owns 32 output cols [32*jgrp, +32) in two 16-col subtiles (js).
// Waves: role = wave>>1 (0: h-side Whh+Wya, 1: a-side Waa+epilogue); js = wave&1.
// Lagged: step t computes h_t and a_{t-1} -> one 16-WG barrier per step.
// Cross-WG state moves via relaxed agent-scope atomics (coherence-point access,
// no acquire/release cache invalidates -> L2 stays warm for xw/weights).
// Double-buffer safety: no WG passes barrier t+1 until all 16 WGs incremented
// for step t+1, which happens only after each finished READING step-t state.
__global__ __launch_bounds__(256) void scan_mfma(const float* __restrict__ xw,
                                                 const unsigned short* __restrict__ Whh_b,
                                                 const unsigned short* __restrict__ Wya_b,
                                                 const unsigned short* __restrict__ Waa_b,
                                                 const float* __restrict__ b_ya,
                                                 const float* __restrict__ b_aa,
                                                 unsigned short* __restrict__ hb,   // 2*64*512 bf16
                                                 unsigned short* __restrict__ ab,   // 2*64*512 bf16
                                                 int* __restrict__ ctr,             // 4 counters, 256B apart
                                                 float* __restrict__ out) {
    const int wg   = blockIdx.x;
    const int bg   = wg >> 4;
    const int jgrp = wg & 15;
    const int j0   = jgrp * 32;
    const int b0   = bg * 16;
    const int tid  = threadIdx.x;
    const int wave = tid >> 6;
    const int lane = tid & 63;
    const int l15  = lane & 15;
    const int quad = lane >> 4;
    const int js   = wave & 1;
    const int role = wave >> 1;
    const int jbase = j0 + js * 16;

    __shared__ unsigned short wlds[3 * 2 * 16 * 64 * 8];  // 96 KB  [mat][js][kb][lane][8]
    __shared__ float pya[2][256];                          // Wya·h partials per subtile
    __shared__ unsigned short hpk[2][256];                 // h C-tile repack staging
    __shared__ unsigned short apk[2][256];                 // a C-tile repack staging

    // Stage weight B-fragments once (cached loads; prior kernels' results are
    // visible via end-of-dispatch release).
    {
        const unsigned short* wsrc[3] = {Whh_b, Wya_b, Waa_b};
        for (int idx = wave; idx < 96; idx += 4) {
            int mat = idx >> 5;
            int rem = idx & 31;
            int jsx = rem >> 4;
            int kb  = rem & 15;
            const unsigned short* src = wsrc[mat] + (size_t)(j0 + jsx * 16 + l15) * H_ + kb * 32 + quad * 8;
            *(uint4*)&wlds[(((mat * 2 + jsx) * 16 + kb) * 64 + lane) * 8] = *(const uint4*)src;
        }
    }
    const float bias_a = b_ya[jbase + l15] + b_aa[jbase + l15];
    int* myctr = ctr + bg * 64;
    __syncthreads();

    for (int t = 1; t <= S_ + 1; ++t) {
        f32x4 acca = {0.f, 0.f, 0.f, 0.f};

        if (role == 0) {
            // xw for this step issued first: L2-hit latency hides under the
            // coherent state loads + MFMA chain.
            float xwv[4];
            if (t <= S_) {
#pragma unroll
                for (int r = 0; r < 4; ++r)
                    xwv[r] = xw[((size_t)(t - 1) * B_ + b0 + quad * 4 + r) * H_ + jbase + l15];
            }
            // h_{t-1} A-frags via coherent u64 loads (32 in flight, one RT)
            const uint64_t* hsrc = (const uint64_t*)hb + ((size_t)((t - 1) & 1)) * (B_ * H_ / 4)
                                   + (size_t)(b0 + l15) * (H_ / 4) + quad * 2;
            union HU { uint64_t q[2]; bf16x8 v; } hf[16];
#pragma unroll
            for (int kb = 0; kb < 16; ++kb) {
                hf[kb].q[0] = __hip_atomic_load(hsrc + kb * 8,     __ATOMIC_RELAXED, __HIP_MEMORY_SCOPE_AGENT);
                hf[kb].q[1] = __hip_atomic_load(hsrc + kb * 8 + 1, __ATOMIC_RELAXED, __HIP_MEMORY_SCOPE_AGENT);
            }
            f32x4 acch = {0.f, 0.f, 0.f, 0.f};
            f32x4 accy = {0.f, 0.f, 0.f, 0.f};
#pragma unroll
            for (int kb = 0; kb < 16; ++kb) {
                bf16x8 bh = *(const bf16x8*)&wlds[(((0 * 2 + js) * 16 + kb) * 64 + lane) * 8];
                bf16x8 by = *(const bf16x8*)&wlds[(((1 * 2 + js) * 16 + kb) * 64 + lane) * 8];
                acch = __builtin_amdgcn_mfma_f32_16x16x32_bf16(hf[kb].v, bh, acch, 0, 0, 0);
                accy = __builtin_amdgcn_mfma_f32_16x16x32_bf16(hf[kb].v, by, accy, 0, 0, 0);
            }
#pragma unroll
            for (int r = 0; r < 4; ++r)
                pya[js][(quad * 4 + r) * 16 + l15] = accy[r];
            if (t <= S_) {
#pragma unroll
                for (int r = 0; r < 4; ++r)
                    hpk[js][(quad * 4 + r) * 16 + l15] = f2b(tanhf(xwv[r] + acch[r]));
                // Intra-wave LDS repack: HW keeps DS ops in order; the fence
                // stops the COMPILER from hoisting the u64 read above the u16
                // writes (uint64_t does not TBAA-alias unsigned short — this
                // was round 3's correctness bug).
                lds_repack_fence();
                uint64_t val = ((const uint64_t*)&hpk[js][0])[lane];
                uint64_t* hdst = (uint64_t*)hb + ((size_t)(t & 1)) * (B_ * H_ / 4)
                                 + (size_t)(b0 + (lane >> 2)) * (H_ / 4) + (jbase >> 2) + (lane & 3);
                __hip_atomic_store(hdst, val, __ATOMIC_RELAXED, __HIP_MEMORY_SCOPE_AGENT);
            }
        } else if (t >= 2) {
            // a_{t-2} A-frags (buffer (t-2)&1 == t&1)
            const uint64_t* asrc = (const uint64_t*)ab + ((size_t)(t & 1)) * (B_ * E_ / 4)
                                   + (size_t)(b0 + l15) * (E_ / 4) + quad * 2;
            union AU { uint64_t q[2]; bf16x8 v; } af[16];
#pragma unroll
            for (int kb = 0; kb < 16; ++kb) {
                af[kb].q[0] = __hip_atomic_load(asrc + kb * 8,     __ATOMIC_RELAXED, __HIP_MEMORY_SCOPE_AGENT);
                af[kb].q[1] = __hip_atomic_load(asrc + kb * 8 + 1, __ATOMIC_RELAXED, __HIP_MEMORY_SCOPE_AGENT);
            }
#pragma unroll
            for (int kb = 0; kb < 16; ++kb) {
                bf16x8 ba = *(const bf16x8*)&wlds[(((2 * 2 + js) * 16 + kb) * 64 + lane) * 8];
                acca = __builtin_amdgcn_mfma_f32_16x16x32_bf16(af[kb].v, ba, acca, 0, 0, 0);
            }
        }
        __syncthreads();   // pya visible to a-side

        if (role == 1 && t >= 2) {
#pragma unroll
            for (int r = 0; r < 4; ++r) {
                int row = quad * 4 + r;
                float av = tanhf(acca[r] + pya[js][row * 16 + l15] + bias_a);
                if (t <= S_)
                    apk[js][row * 16 + l15] = f2b(av);
                else
                    out[(size_t)(b0 + row) * E_ + jbase + l15] = av;
            }
            if (t <= S_) {
                lds_repack_fence();   // same TBAA hazard as hpk
                uint64_t val = ((const uint64_t*)&apk[js][0])[lane];
                uint64_t* adst = (uint64_t*)ab + ((size_t)((t - 1) & 1)) * (B_ * E_ / 4)
                                 + (size_t)(b0 + (lane >> 2)) * (E_ / 4) + (jbase >> 2) + (lane & 3);
                __hip_atomic_store(adst, val, __ATOMIC_RELAXED, __HIP_MEMORY_SCOPE_AGENT);
            }
        }

        if (t <= S_) {
            __syncthreads();   // emits s_waitcnt vmcnt(0) -> all WG stores at coherence point
            if (tid == 0) {
                // RELEASE: publish edge for this WG's stores (waitcnt only at
                // agent scope — no buffer_inv/wbl2, L2 stays warm).
                __hip_atomic_fetch_add(myctr, 1, __ATOMIC_RELEASE, __HIP_MEMORY_SCOPE_AGENT);
                while (__hip_atomic_load(myctr, __ATOMIC_RELAXED, __HIP_MEMORY_SCOPE_AGENT) < GRP_WGS * t) {}
            }
            __syncthreads();
            __atomic_signal_fence(__ATOMIC_SEQ_CST);  // compiler-only; post-poll data
                                                      // loads are themselves coherent
        }
    }
}

extern "C" void kernel_launch(void* const* d_in, const int* in_sizes, int n_in,
                              void* d_out, int out_size, void* d_ws, size_t ws_size,
                              hipStream_t stream) {
    const float* x    = (const float*)d_in[0];
    const float* W_ih = (const float*)d_in[1];
    const float* W_hh = (const float*)d_in[2];
    const float* b_ih = (const float*)d_in[3];
    const float* b_hh = (const float*)d_in[4];
    const float* W_ya = (const float*)d_in[5];
    const float* b_ya = (const float*)d_in[6];
    const float* W_aa = (const float*)d_in[7];
    const float* b_aa = (const float*)d_in[8];
    float* out = (float*)d_out;

    char* ws = (char*)d_ws;
    const size_t MB = 1024 * 1024;
    float*          xw    = (float*)(ws);                                  // 64 MB
    unsigned short* Whh_b = (unsigned short*)(ws + 64 * MB);               // 512 KB
    unsigned short* Wya_b = (unsigned short*)(ws + 64 * MB + 512 * 1024);  // 512 KB
    unsigned short* Waa_b = (unsigned short*)(ws + 65 * MB);               // 512 KB
    unsigned short* hb    = (unsigned short*)(ws + 65 * MB + 512 * 1024);  // 128 KB
    unsigned short* ab    = (unsigned short*)(ws + 65 * MB + 640 * 1024);  // 128 KB
    int*            ctr   = (int*)(ws + 66 * MB);                          // 4 KB

    conv_bf16<<<(H_ * H_) / 256, 256, 0, stream>>>(W_hh, W_ya, W_aa, Whh_b, Wya_b, Waa_b);

    // zero hb+ab (contiguous 256 KB = 65536 u32) and counters
    init_state<<<256, 256, 0, stream>>>((uint32_t*)hb, 65536);
    init_state<<<4,   256, 0, stream>>>((uint32_t*)ctr, 1024);

    dim3 gg(H_ / 64, (S_ * B_) / 64);
    xw_gemm<<<gg, 256, 0, stream>>>(x, W_ih, b_ih, b_hh, xw);

    scan_mfma<<<64, 256, 0, stream>>>(xw, Whh_b, Wya_b, Waa_b, b_ya, b_aa,
                                      hb, ab, ctr, out);
}